// Round 2
// baseline (183.720 us; speedup 1.0000x reference)
//
#include <hip/hip_runtime.h>

#define TT 2048
#define VV 1024
#define BB 8
#define BLOCK 256
#define WPB 4   // waves per block (wave64)

// One WAVE per (b, t). Wave-synchronous scan: no __syncthreads at all.
//   c = idx[b,t]
//   L(s) = w2*cnt_c(s) + (w0-w2)*[idx[s]==c] + (w1-w2)*[idx[s-1]==c],  s <= t
//   logits[v] = sum_{s<=t, idx[s]==v} L(s)   (LDS scatter, 4KB slab per wave)
// then shuffle-only softmax over V=1024 (16 values/lane) and coalesced store.
__global__ __launch_bounds__(BLOCK) void min_model_kernel(
    const int* __restrict__ idx, const float* __restrict__ w,
    float* __restrict__ out)
{
    __shared__ float logits[WPB][VV];

    const int tid  = threadIdx.x;
    const int lane = tid & 63;
    const int wid  = tid >> 6;
    const int wg   = blockIdx.x * WPB + wid;    // global (b,t) index
    const int b    = wg >> 11;                  // / TT
    const int t    = wg & (TT - 1);             // % TT

    const int* __restrict__ row = idx + b * TT;
    const int c  = row[t];
    const float w2  = w[2];
    const float dw0 = w[0] - w2, dw1 = w[1] - w2;

    float* __restrict__ lg = logits[wid];
    // zero this wave's slab: strided (bank = lane%32, 2-way = free)
    #pragma unroll
    for (int j = 0; j < VV / 64; ++j) lg[j * 64 + lane] = 0.0f;

    // scan s = 0..t in wave-sized chunks; carry is wave-uniform in registers
    int carry = 0;
    int prev_last = -1;                          // row[chunk_base - 1]
    const int niter = (t >> 6) + 1;
    for (int it = 0; it < niter; ++it) {
        const int s = (it << 6) + lane;
        const bool valid = (s <= t);
        int tok = valid ? row[s] : -1;
        int tokp = __shfl_up(tok, 1, 64);
        if (lane == 0) tokp = prev_last;
        prev_last = __shfl(tok, 63, 64);

        const int f  = (tok  == c) ? 1 : 0;
        const int fp = (tokp == c) ? 1 : 0;
        const unsigned long long bal = __ballot(f != 0);
        const int pre = __popcll(bal & ((1ULL << lane) - 1ULL));
        const int cnt = carry + pre + f;        // inclusive count of c in row[0..s]

        if (valid) {
            const float L = w2 * (float)cnt + dw0 * (float)f + dw1 * (float)fp;
            atomicAdd(&lg[tok], L);
        }
        carry += __popcll(bal);
    }

    // DS pipe is in-order per wave, but be explicit: drain atomics before reads
    asm volatile("s_waitcnt lgkmcnt(0)" ::: "memory");

    // ---- softmax over V=1024: 16 strided values per lane, shuffle reductions ----
    float v[16];
    float m = -1e30f;
    #pragma unroll
    for (int j = 0; j < 16; ++j) {
        v[j] = lg[j * 64 + lane];
        m = fmaxf(m, v[j]);
    }
    #pragma unroll
    for (int o = 32; o > 0; o >>= 1) m = fmaxf(m, __shfl_xor(m, o, 64));

    float sm = 0.0f;
    #pragma unroll
    for (int j = 0; j < 16; ++j) { v[j] = __expf(v[j] - m); sm += v[j]; }
    #pragma unroll
    for (int o = 32; o > 0; o >>= 1) sm += __shfl_xor(sm, o, 64);
    const float inv = 1.0f / sm;

    // coalesced store: each scalar store = 64 lanes x 4B contiguous
    float* __restrict__ op = out + ((size_t)wg << 10);
    #pragma unroll
    for (int j = 0; j < 16; ++j) op[j * 64 + lane] = v[j] * inv;
}

extern "C" void kernel_launch(void* const* d_in, const int* in_sizes, int n_in,
                              void* d_out, int out_size, void* d_ws, size_t ws_size,
                              hipStream_t stream) {
    const int*   idx = (const int*)d_in[0];
    const float* w   = (const float*)d_in[1];
    float*       out = (float*)d_out;
    min_model_kernel<<<(BB * TT) / WPB, BLOCK, 0, stream>>>(idx, w, out);
}

// Round 3
// 172.107 us; speedup vs baseline: 1.0675x; 1.0675x over previous
//
#include <hip/hip_runtime.h>

#define TT 2048
#define VV 1024
#define BB 8
#define BLOCK 256
#define WPB 4    // waves per block (wave64)
#define NCH 32   // TT / 64 chunks per row

// One WAVE per (b, t). Whole token row preloaded into registers (32/lane);
// scan loop has NO memory loads and NO shuffles:
//   prev-token flag = ballot shifted by one bit (SGPR math),
//   prefix count    = popcount(ballot & lanemask) + running SALU carry.
// Only the ds_add_f32 scatter touches memory, off the critical path.
__global__ __launch_bounds__(BLOCK) void min_model_kernel(
    const int* __restrict__ idx, const float* __restrict__ w,
    float* __restrict__ out)
{
    __shared__ float logits[WPB][VV];

    const int tid  = threadIdx.x;
    const int lane = tid & 63;
    const int wid  = tid >> 6;
    const int wg   = blockIdx.x * WPB + wid;    // global (b,t)
    const int b    = wg >> 11;                  // / TT
    const int t    = wg & (TT - 1);             // % TT

    const int* __restrict__ row = idx + b * TT;

    // ---- preload entire row into registers: tok_all[it] = row[it*64 + lane]
    int tok_all[NCH];
    #pragma unroll
    for (int it = 0; it < NCH; ++it) tok_all[it] = row[it * 64 + lane];

    const int c    = row[t];
    const float w2  = w[2];
    const float dw0 = w[0] - w2, dw1 = w[1] - w2;

    float*  __restrict__ lg  = logits[wid];
    float4* __restrict__ lg4 = (float4*)lg;
    #pragma unroll
    for (int j = 0; j < 4; ++j)
        lg4[j * 64 + lane] = float4{0.f, 0.f, 0.f, 0.f};   // 2-way bank alias, free

    const unsigned long long lmask = (1ULL << lane) - 1ULL;
    const int tmax = t >> 6;                     // last chunk index
    int carry = 0;                               // count of c in fully-done chunks
    unsigned long long carry_bit = 0;            // prev chunk's bit63, at bit0

    #pragma unroll
    for (int it = 0; it < NCH; ++it) {
        if (it <= tmax) {                        // wave-uniform guard (s_cbranch)
            const int s   = (it << 6) + lane;
            const int tok = tok_all[it];
            const bool fb = (tok == c);
            const unsigned long long bal  = __ballot(fb);
            const unsigned long long balp = (bal << 1) | carry_bit;
            const int f  = fb ? 1 : 0;
            const int fp = (int)((balp >> lane) & 1ULL);
            const int cnt = carry + __popcll(bal & lmask) + f;  // inclusive count
            if (s <= t) {
                const float L = fmaf((float)f, dw0,
                                fmaf((float)fp, dw1, w2 * (float)cnt));
                atomicAdd(&lg[tok], L);
            }
            // lanes with s>t only pollute bits above valid lanes in the LAST
            // chunk, after which the loop ends -> harmless.
            carry += __popcll(bal);
            carry_bit = bal >> 63;
        }
    }

    // DS pipe is in-order per wave; fence so the compiler doesn't hoist reads
    asm volatile("s_waitcnt lgkmcnt(0)" ::: "memory");

    // ---- softmax over V=1024: 4x float4 per lane, shuffle reductions ----
    float4 v4[4];
    float m = -1e30f;
    #pragma unroll
    for (int j = 0; j < 4; ++j) {
        v4[j] = lg4[j * 64 + lane];
        m = fmaxf(m, fmaxf(fmaxf(v4[j].x, v4[j].y), fmaxf(v4[j].z, v4[j].w)));
    }
    #pragma unroll
    for (int o = 32; o > 0; o >>= 1) m = fmaxf(m, __shfl_xor(m, o, 64));

    float sm = 0.0f;
    #pragma unroll
    for (int j = 0; j < 4; ++j) {
        v4[j].x = __expf(v4[j].x - m);
        v4[j].y = __expf(v4[j].y - m);
        v4[j].z = __expf(v4[j].z - m);
        v4[j].w = __expf(v4[j].w - m);
        sm += v4[j].x + v4[j].y + v4[j].z + v4[j].w;
    }
    #pragma unroll
    for (int o = 32; o > 0; o >>= 1) sm += __shfl_xor(sm, o, 64);
    const float inv = 1.0f / sm;

    // coalesced float4 store: 64 lanes x 16B contiguous = 1KB per instr
    float4* __restrict__ op4 = (float4*)(out + ((size_t)wg << 10));
    #pragma unroll
    for (int j = 0; j < 4; ++j) {
        float4 o4 = { v4[j].x * inv, v4[j].y * inv, v4[j].z * inv, v4[j].w * inv };
        op4[j * 64 + lane] = o4;
    }
}

extern "C" void kernel_launch(void* const* d_in, const int* in_sizes, int n_in,
                              void* d_out, int out_size, void* d_ws, size_t ws_size,
                              hipStream_t stream) {
    const int*   idx = (const int*)d_in[0];
    const float* w   = (const float*)d_in[1];
    float*       out = (float*)d_out;
    min_model_kernel<<<(BB * TT) / WPB, BLOCK, 0, stream>>>(idx, w, out);
}

// Round 4
// 102.900 us; speedup vs baseline: 1.7854x; 1.6726x over previous
//
#include <hip/hip_runtime.h>

#define TT   2048
#define VV   1024
#define BB   8
#define NSEG 32      // 64-position segments per row
#define ROCC 32      // occurrence slots per (b,c); P(overflow) ~ 1e-25

// ws layout:
//   SEGP f32[BB][NSEG][VV]  exclusive prefix histograms   @ 0        (1 MB)
//   SEGH f32[BB][NSEG][VV]  per-segment histograms        @ 1 MB     (1 MB)
//   RANK i32[BB][TT]        inclusive rank of idx[t]      @ 2 MB     (64 KB)
//   OCC  i32[BB][VV][ROCC]  occurrence positions          @ 2 MB+64K (1 MB)
#define SEGP_OFF 0
#define SEGH_OFF (1u << 20)
#define RANK_OFF (2u << 20)
#define OCC_OFF  ((2u << 20) + (1u << 16))

// K1: per-(b,g) segment histogram (one wave per block).
__global__ __launch_bounds__(64) void k_seghist(const int* __restrict__ idx,
                                                float* __restrict__ SEGH) {
    __shared__ float h[VV];
    const int bg = blockIdx.x, b = bg >> 5, g = bg & 31, lane = threadIdx.x;
    #pragma unroll
    for (int j = 0; j < 16; ++j) h[j * 64 + lane] = 0.0f;
    __syncthreads();
    const int x = idx[b * TT + (g << 6) + lane];
    atomicAdd(&h[x], 1.0f);
    __syncthreads();
    float* o = SEGH + (size_t)(b * NSEG + g) * VV;
    #pragma unroll
    for (int j = 0; j < 16; ++j) o[j * 64 + lane] = h[j * 64 + lane];
}

// K2: per-b exclusive prefix over segments (histograms live in registers).
__global__ __launch_bounds__(256) void k_segprefix(const float* __restrict__ SEGH,
                                                   float* __restrict__ SEGP) {
    const int b = blockIdx.x, tid = threadIdx.x;
    float r0 = 0, r1 = 0, r2 = 0, r3 = 0;
    for (int g = 0; g < NSEG; ++g) {
        const size_t o = (size_t)(b * NSEG + g) * VV;
        SEGP[o + tid      ] = r0;  SEGP[o + tid + 256] = r1;
        SEGP[o + tid + 512] = r2;  SEGP[o + tid + 768] = r3;
        r0 += SEGH[o + tid      ];  r1 += SEGH[o + tid + 256];
        r2 += SEGH[o + tid + 512];  r3 += SEGH[o + tid + 768];
    }
}

// K3: per-position inclusive rank + per-class occurrence list (conflict-free).
__global__ __launch_bounds__(64) void k_rank(const int* __restrict__ idx,
                                             const float* __restrict__ SEGP,
                                             int* __restrict__ RANK,
                                             int* __restrict__ OCC) {
    const int bg = blockIdx.x, b = bg >> 5, g = bg & 31, lane = threadIdx.x;
    const int s = (g << 6) + lane;
    const int x = idx[b * TT + s];
    const int base = (int)SEGP[(size_t)(b * NSEG + g) * VV + x];
    int cnt = 0;
    for (int i = 0; i < 64; ++i) {
        const int xi = __shfl(x, i, 64);
        cnt += (i < lane && xi == x) ? 1 : 0;
    }
    const int rank = base + cnt + 1;                 // inclusive
    RANK[b * TT + s] = rank;
    if (rank - 1 < ROCC) OCC[((size_t)b * VV + x) * ROCC + (rank - 1)] = s;
}

// Main: one wave per (b,t).
//   logits_v = w2*(K*N_v(t) - sum_j N_v(u_j-1)) + dw1*bigram + dw0*K*[v=c]
// Snapshot N = dense SEGP row (coalesced global, register adds)
//            + <=64-lane partial-segment LDS scatter (integer weights, exact).
__global__ __launch_bounds__(256) void k_main(const int* __restrict__ idx,
                                              const float* __restrict__ w,
                                              const float* __restrict__ SEGP,
                                              const int* __restrict__ RANK,
                                              const int* __restrict__ OCC,
                                              float* __restrict__ out) {
    __shared__ float slab[4][VV];
    const int tid = threadIdx.x, lane = tid & 63, wid = tid >> 6;
    const int wg = blockIdx.x * 4 + wid;
    const int b = wg >> 11, t = wg & (TT - 1);

    const int* __restrict__ row = idx + b * TT;
    const int c = row[t];
    const int K = RANK[b * TT + t];
    const float w2 = w[2], dw0 = w[0] - w2, dw1 = w[1] - w2;
    const float Kf = (float)K;

    float* __restrict__ lg = slab[wid];              // wave-private: no barriers
    #pragma unroll
    for (int j = 0; j < 16; ++j) lg[j * 64 + lane] = 0.0f;

    const float* __restrict__ segp_b = SEGP + (size_t)b * NSEG * VV;
    const int gt = t >> 6;

    // dense: acc = K * SEGP[g(t)]           (coalesced, 4B/lane, lane-minor)
    float acc[16];
    {
        const float* __restrict__ pr = segp_b + (size_t)gt * VV;
        #pragma unroll
        for (int j = 0; j < 16; ++j) acc[j] = Kf * pr[j * 64 + lane];
    }
    // own partial [64*gt, t]: weight +K
    if (lane <= (t & 63)) atomicAdd(&lg[row[(gt << 6) + lane]], Kf);

    // snapshots at occurrences (wave-uniform loop, K avg ~2)
    const int* __restrict__ occ = OCC + ((size_t)b * VV + c) * ROCC;
    for (int j = 0; j < K; ++j) {
        const int p = occ[j] - 1;
        if (p >= 0) {
            const int gp = p >> 6;
            const float* __restrict__ pr = segp_b + (size_t)gp * VV;
            #pragma unroll
            for (int q = 0; q < 16; ++q) acc[q] -= pr[q * 64 + lane];
            if (lane <= (p & 63)) atomicAdd(&lg[row[(gp << 6) + lane]], -1.0f);
        }
    }

    asm volatile("s_waitcnt lgkmcnt(0)" ::: "memory");

    // combine (exact integer counts scaled once by w2)
    float lo[16];
    #pragma unroll
    for (int j = 0; j < 16; ++j) lo[j] = w2 * (acc[j] + lg[j * 64 + lane]);

    // self term: +dw0*K at v=c
    #pragma unroll
    for (int j = 0; j < 16; ++j)
        lo[j] += ((c >> 6) == j && (c & 63) == lane) ? dw0 * Kf : 0.0f;

    // bigram: +dw1 at v=idx[u_j+1] for occurrences u_j < t (occ[K-1]==t)
    for (int j = 0; j < K - 1; ++j) {
        const int xn = row[occ[j] + 1];
        #pragma unroll
        for (int q = 0; q < 16; ++q)
            lo[q] += ((xn >> 6) == q && (xn & 63) == lane) ? dw1 : 0.0f;
    }

    // ---- softmax over V=1024 (shuffle reductions) ----
    float m = -1e30f;
    #pragma unroll
    for (int j = 0; j < 16; ++j) m = fmaxf(m, lo[j]);
    #pragma unroll
    for (int o = 32; o > 0; o >>= 1) m = fmaxf(m, __shfl_xor(m, o, 64));
    float sm = 0.0f;
    #pragma unroll
    for (int j = 0; j < 16; ++j) { lo[j] = __expf(lo[j] - m); sm += lo[j]; }
    #pragma unroll
    for (int o = 32; o > 0; o >>= 1) sm += __shfl_xor(sm, o, 64);
    const float inv = 1.0f / sm;

    float* __restrict__ op = out + ((size_t)wg << 10);
    #pragma unroll
    for (int j = 0; j < 16; ++j) op[j * 64 + lane] = lo[j] * inv;
}

extern "C" void kernel_launch(void* const* d_in, const int* in_sizes, int n_in,
                              void* d_out, int out_size, void* d_ws, size_t ws_size,
                              hipStream_t stream) {
    const int*   idx = (const int*)d_in[0];
    const float* w   = (const float*)d_in[1];
    float*       out = (float*)d_out;
    char* ws = (char*)d_ws;                      // needs ~3.1 MB
    float* SEGP = (float*)(ws + SEGP_OFF);
    float* SEGH = (float*)(ws + SEGH_OFF);
    int*   RANK = (int*)(ws + RANK_OFF);
    int*   OCC  = (int*)(ws + OCC_OFF);

    k_seghist  <<<BB * NSEG, 64,  0, stream>>>(idx, SEGH);
    k_segprefix<<<BB,        256, 0, stream>>>(SEGH, SEGP);
    k_rank     <<<BB * NSEG, 64,  0, stream>>>(idx, SEGP, RANK, OCC);
    k_main     <<<(BB * TT) / 4, 256, 0, stream>>>(idx, w, SEGP, RANK, OCC, out);
}